// Round 6
// baseline (213.440 us; speedup 1.0000x reference)
//
#include <hip/hip_runtime.h>
#include <hip/hip_bf16.h>

// IsometricLoss: loss = (1/N) * sum_{i,m} r[i,m] * max(||X_i||^2 + ||mu_m||^2 - 2 X_i.mu_m, 0)
// N=131072, M=128, D=128, fp32 in, fp32 scalar out.
//
// R9: same verified algebra/layout as R8 (zero LDS, zero barriers, augmented
// musT' [144x128] table, 16x16x32 MFMA), rescheduled for Little's law: HBM needs
// ~9.2 KB in flight per CU continuously; R7/R8 averaged 1-2 KB -> 1.1 TB/s.
// Each wave owns TWO 16-row chunks, straight-line software pipeline:
//   issue rA+xA (1 KB in flight) -> pack bfragA -> issue rB (flies under chunk A)
//   -> chunk A -> issue xB -> pack bfragB -> chunk B.
// __launch_bounds__(256,4): 128-reg cap vs ~120 peak WITH loads in flight
// (R4/R5/R8 died counting steady-state regs, not the in-flight peak).
// grid 1024 x 256 = 4096 waves = 16/CU resident in one round.

typedef __attribute__((ext_vector_type(8))) short  short8;   // 8 bf16 (MFMA A/B frag)
typedef __attribute__((ext_vector_type(4))) float  float4v;  // MFMA 16x16 accumulator

#if defined(__has_builtin)
#if __has_builtin(__builtin_amdgcn_cvt_pk_bf16_f32)
#define HAVE_PK_BF16 1
#endif
#endif

__device__ __forceinline__ unsigned int pk_bf16(float x, float y) {
#ifdef HAVE_PK_BF16
    typedef __attribute__((ext_vector_type(2))) __bf16 bf16x2;
    bf16x2 p = __builtin_amdgcn_cvt_pk_bf16_f32(x, y);
    return __builtin_bit_cast(unsigned int, p);
#else
    unsigned int ux = __float_as_uint(x);
    unsigned int uy = __float_as_uint(y);
    ux += 0x7fffu + ((ux >> 16) & 1u);
    uy += 0x7fffu + ((uy >> 16) & 1u);
    return (ux >> 16) | (uy & 0xffff0000u);
#endif
}

__global__ void final_reduce_kernel(const float* ws, float* out) {
    const int lane = threadIdx.x;  // 64 threads
    float t = ws[lane];
    #pragma unroll
    for (int off = 32; off > 0; off >>= 1) t += __shfl_down(t, off);
    if (lane == 0) out[0] = t * (1.0f / 131072.0f);
}

// Prelude: lane-packed A-fragment table for musT' [144 x 128] bf16.
// Entry g = (dt*4 + ks)*64 + lane holds 8 bf16:
//   musT'[dt*16 + (lane&15)][ks*32 + (lane>>4)*8 + e],  dt=0..8, ks=0..3.
// Rows: 0..127 = mus^T, 128 = mu2 (exact fp32), 129 = ones, 130..143 = 0.
// Block 0 also zeroes the 64 reduction buckets.
__global__ __launch_bounds__(256)
void build_afrag_kernel(const float* __restrict__ mus, uint4* __restrict__ afrag,
                        float* __restrict__ ws)
{
    const int g = blockIdx.x * 256 + threadIdx.x;   // 0..2303 (9 blocks)
    if (blockIdx.x == 0 && threadIdx.x < 64) ws[threadIdx.x] = 0.0f;

    const int dt   = g >> 8;         // 0..8
    const int ks   = (g >> 6) & 3;
    const int lane = g & 63;
    const int dp   = dt * 16 + (lane & 15);          // d' in [0,144)
    const int m0   = ks * 32 + (lane >> 4) * 8;      // m base

    float v[8];
    if (dp < 128) {
        #pragma unroll
        for (int e = 0; e < 8; ++e)
            v[e] = mus[(size_t)(m0 + e) * 128 + dp];       // musT[d'][m] = mus[m][d']
    } else if (dp == 128) {                                // mu2 row (exact fp32 sums)
        #pragma unroll
        for (int e = 0; e < 8; ++e) {
            const float4* row = (const float4*)(mus + (size_t)(m0 + e) * 128);
            float a = 0.0f;
            #pragma unroll 8
            for (int d4 = 0; d4 < 32; ++d4) {
                const float4 t = row[d4];
                a += t.x*t.x + t.y*t.y + t.z*t.z + t.w*t.w;
            }
            v[e] = a;
        }
    } else if (dp == 129) {                                // ones row -> rrow
        #pragma unroll
        for (int e = 0; e < 8; ++e) v[e] = 1.0f;
    } else {                                               // zero pad rows 130..143
        #pragma unroll
        for (int e = 0; e < 8; ++e) v[e] = 0.0f;
    }

    uint4 u;
    u.x = pk_bf16(v[0], v[1]);
    u.y = pk_bf16(v[2], v[3]);
    u.z = pk_bf16(v[4], v[5]);
    u.w = pk_bf16(v[6], v[7]);
    afrag[g] = u;
}

// One 16-row chunk: 9 d'-tiles of mfma(afrag_tile, BFRAG) + fused epilogue.
// Zero-pad rows in the table make the aug accumulations correct on all kg lanes.
#define CHUNK(BFRAG, XQ, DOTP, X2P, RMU2, RROW)                                          \
    {                                                                                    \
        _Pragma("unroll")                                                                \
        for (int dt = 0; dt < 9; ++dt) {                                                 \
            short8 af[4];                                                                \
            _Pragma("unroll")                                                            \
            for (int ks = 0; ks < 4; ++ks)                                               \
                af[ks] = ((const short8*)afrag)[(dt * 4 + ks) * 64 + lane];              \
            float4v acc = {};                                                            \
            _Pragma("unroll")                                                            \
            for (int ks = 0; ks < 4; ++ks)                                               \
                acc = __builtin_amdgcn_mfma_f32_16x16x32_bf16(af[ks], BFRAG[ks], acc, 0, 0, 0); \
            if (dt < 8) {                                                                \
                const float4 xq = XQ[dt];                                                \
                DOTP += xq.x*acc[0] + xq.y*acc[1] + xq.z*acc[2] + xq.w*acc[3];           \
                X2P  += xq.x*xq.x + xq.y*xq.y + xq.z*xq.z + xq.w*xq.w;                   \
            } else {                                                                     \
                RMU2 += acc[0];  /* d'=128+kg*4: mu2 row on kg==0, zero rows else */     \
                RROW += acc[1];  /* d'=129+kg*4: ones row on kg==0, zero rows else */    \
            }                                                                            \
        }                                                                                \
    }

// Main: 1024 blocks x 256 threads = 4096 waves; wave wv owns rows [wv*32, wv*32+32)
// as two 16-row chunks A and B, software-pipelined. No LDS, no barriers.
__global__ __launch_bounds__(256, 4)
void isoloss_kernel(const float* __restrict__ X,
                    const float* __restrict__ r,
                    const uint4* __restrict__ afrag,
                    float* __restrict__ ws)
{
    const int tid  = threadIdx.x;
    const int wv   = blockIdx.x * 4 + (tid >> 6);   // global wave 0..4095
    const int lane = tid & 63;
    const int li   = lane & 15;                     // row-in-chunk i (C col)
    const int kg   = lane >> 4;                     // k-group 0..3 (C row-group)

    const size_t iA = (size_t)wv * 32 + li;         // chunk A row
    const float* rA_p = r + iA * 128 + kg * 8;
    const float* xA_p = X + iA * 128 + kg * 4;
    const float* rB_p = rA_p + 16 * 128;
    const float* xB_p = xA_p + 16 * 128;

    // ---- issue chunk-A r AND X loads immediately (1 KB/lane-wave in flight) ----
    float4 ra[8];
    #pragma unroll
    for (int ks = 0; ks < 4; ++ks) {
        ra[2*ks]   = *(const float4*)(rA_p + ks * 32);
        ra[2*ks+1] = *(const float4*)(rA_p + ks * 32 + 4);
    }
    float4 xa[8];
    #pragma unroll
    for (int dt = 0; dt < 8; ++dt)
        xa[dt] = *(const float4*)(xA_p + dt * 16);

    // ---- pack A bfrag (first wait), then issue chunk-B r to fly under chunk A ----
    short8 bfragA[4];
    #pragma unroll
    for (int ks = 0; ks < 4; ++ks) {
        union { short8 s8; uint4 u4; } u;
        u.u4.x = pk_bf16(ra[2*ks].x,   ra[2*ks].y);
        u.u4.y = pk_bf16(ra[2*ks].z,   ra[2*ks].w);
        u.u4.z = pk_bf16(ra[2*ks+1].x, ra[2*ks+1].y);
        u.u4.w = pk_bf16(ra[2*ks+1].z, ra[2*ks+1].w);
        bfragA[ks] = u.s8;
    }
    float4 rb[8];
    #pragma unroll
    for (int ks = 0; ks < 4; ++ks) {
        rb[2*ks]   = *(const float4*)(rB_p + ks * 32);
        rb[2*ks+1] = *(const float4*)(rB_p + ks * 32 + 4);
    }

    // ---- chunk A compute ----
    float dotA = 0.0f, x2A = 0.0f, rmu2A = 0.0f, rrowA = 0.0f;
    CHUNK(bfragA, xa, dotA, x2A, rmu2A, rrowA);

    // ---- issue chunk-B X loads, pack B bfrag (rb arrived during chunk A) ----
    float4 xb[8];
    #pragma unroll
    for (int dt = 0; dt < 8; ++dt)
        xb[dt] = *(const float4*)(xB_p + dt * 16);

    short8 bfragB[4];
    #pragma unroll
    for (int ks = 0; ks < 4; ++ks) {
        union { short8 s8; uint4 u4; } u;
        u.u4.x = pk_bf16(rb[2*ks].x,   rb[2*ks].y);
        u.u4.y = pk_bf16(rb[2*ks].z,   rb[2*ks].w);
        u.u4.z = pk_bf16(rb[2*ks+1].x, rb[2*ks+1].y);
        u.u4.w = pk_bf16(rb[2*ks+1].z, rb[2*ks+1].w);
        bfragB[ks] = u.s8;
    }

    // ---- chunk B compute ----
    float dotB = 0.0f, x2B = 0.0f, rmu2B = 0.0f, rrowB = 0.0f;
    CHUNK(bfragB, xb, dotB, x2B, rmu2B, rrowB);

    // ---- per-row x2 completion (butterfly over the 4 kg lanes of each li) ----
    float x2iA = x2A;
    x2iA += __shfl_xor(x2iA, 16);
    x2iA += __shfl_xor(x2iA, 32);
    float x2iB = x2B;
    x2iB += __shfl_xor(x2iB, 16);
    x2iB += __shfl_xor(x2iB, 32);

    // per-lane partial of loss*N
    float s = fmaf(x2iA, rrowA, rmu2A) + fmaf(x2iB, rrowB, rmu2B)
            - 2.0f * (dotA + dotB);

    // ---- wave reduce -> bucketed atomic ----
    #pragma unroll
    for (int off = 32; off > 0; off >>= 1) s += __shfl_down(s, off);
    if (lane == 0) atomicAdd(&ws[blockIdx.x & 63], s);
}

extern "C" void kernel_launch(void* const* d_in, const int* in_sizes, int n_in,
                              void* d_out, int out_size, void* d_ws, size_t ws_size,
                              hipStream_t stream) {
    const float* X   = (const float*)d_in[0];   // [131072, 128]
    const float* r   = (const float*)d_in[1];   // [131072, 128]
    const float* mus = (const float*)d_in[2];   // [128, 128]
    float* out = (float*)d_out;                 // scalar
    float* ws  = (float*)d_ws;                  // [0..64): buckets; +256B: afrag (36 KB)
    uint4* afrag = (uint4*)((char*)d_ws + 256);

    build_afrag_kernel<<<9, 256, 0, stream>>>(mus, afrag, ws);
    isoloss_kernel<<<1024, 256, 0, stream>>>(X, r, afrag, ws);
    final_reduce_kernel<<<1, 64, 0, stream>>>(ws, out);
}

// Round 7
// 188.099 us; speedup vs baseline: 1.1347x; 1.1347x over previous
//
#include <hip/hip_runtime.h>
#include <hip/hip_bf16.h>

// IsometricLoss: loss = (1/N) * sum_{i,m} r[i,m] * max(||X_i||^2 + ||mu_m||^2 - 2 X_i.mu_m, 0)
// N=131072, M=128, D=128, fp32 in, fp32 scalar out.
//
// R10: minimal diff from R8 (which PASSED; its only structural bug was the
// (256,8) register cap -> 12.5 MB spill). Changes:
//  1. __launch_bounds__(256,4): 128-reg cap, the R7-proven-clean config.
//  2. All 8 X float4 loads hoisted to the prologue (20 VMEM in flight/wave
//     vs R8's 8; epilogue never waits on memory).
//  3. af-table double-buffer: afn[dt+1] prefetched while dt's MFMAs run,
//     breaking R8's serial af->MFMA ~200cy stall per d'-tile.
// Peak live set ~105 regs (< 128, R7-clean territory; R9's ~121 spilled).
// Math/layout identical to R8 (verified): zero LDS, zero barriers, augmented
// musT' [144x128] lane-packed table, mfma_f32_16x16x32_bf16.

typedef __attribute__((ext_vector_type(8))) short  short8;   // 8 bf16 (MFMA A/B frag)
typedef __attribute__((ext_vector_type(4))) float  float4v;  // MFMA 16x16 accumulator

#if defined(__has_builtin)
#if __has_builtin(__builtin_amdgcn_cvt_pk_bf16_f32)
#define HAVE_PK_BF16 1
#endif
#endif

__device__ __forceinline__ unsigned int pk_bf16(float x, float y) {
#ifdef HAVE_PK_BF16
    typedef __attribute__((ext_vector_type(2))) __bf16 bf16x2;
    bf16x2 p = __builtin_amdgcn_cvt_pk_bf16_f32(x, y);
    return __builtin_bit_cast(unsigned int, p);
#else
    unsigned int ux = __float_as_uint(x);
    unsigned int uy = __float_as_uint(y);
    ux += 0x7fffu + ((ux >> 16) & 1u);
    uy += 0x7fffu + ((uy >> 16) & 1u);
    return (ux >> 16) | (uy & 0xffff0000u);
#endif
}

__global__ void final_reduce_kernel(const float* ws, float* out) {
    const int lane = threadIdx.x;  // 64 threads
    float t = ws[lane];
    #pragma unroll
    for (int off = 32; off > 0; off >>= 1) t += __shfl_down(t, off);
    if (lane == 0) out[0] = t * (1.0f / 131072.0f);
}

// Prelude: lane-packed A-fragment table for musT' [144 x 128] bf16.
// Entry g = (dt*4 + ks)*64 + lane holds 8 bf16:
//   musT'[dt*16 + (lane&15)][ks*32 + (lane>>4)*8 + e],  dt=0..8, ks=0..3.
// Rows: 0..127 = mus^T, 128 = mu2 (exact fp32), 129 = ones, 130..143 = 0.
// Block 0 also zeroes the 64 reduction buckets.
__global__ __launch_bounds__(256)
void build_afrag_kernel(const float* __restrict__ mus, uint4* __restrict__ afrag,
                        float* __restrict__ ws)
{
    const int g = blockIdx.x * 256 + threadIdx.x;   // 0..2303 (9 blocks)
    if (blockIdx.x == 0 && threadIdx.x < 64) ws[threadIdx.x] = 0.0f;

    const int dt   = g >> 8;         // 0..8
    const int ks   = (g >> 6) & 3;
    const int lane = g & 63;
    const int dp   = dt * 16 + (lane & 15);          // d' in [0,144)
    const int m0   = ks * 32 + (lane >> 4) * 8;      // m base

    float v[8];
    if (dp < 128) {
        #pragma unroll
        for (int e = 0; e < 8; ++e)
            v[e] = mus[(size_t)(m0 + e) * 128 + dp];       // musT[d'][m] = mus[m][d']
    } else if (dp == 128) {                                // mu2 row (exact fp32 sums)
        #pragma unroll
        for (int e = 0; e < 8; ++e) {
            const float4* row = (const float4*)(mus + (size_t)(m0 + e) * 128);
            float a = 0.0f;
            #pragma unroll 8
            for (int d4 = 0; d4 < 32; ++d4) {
                const float4 t = row[d4];
                a += t.x*t.x + t.y*t.y + t.z*t.z + t.w*t.w;
            }
            v[e] = a;
        }
    } else if (dp == 129) {                                // ones row -> rrow
        #pragma unroll
        for (int e = 0; e < 8; ++e) v[e] = 1.0f;
    } else {                                               // zero pad rows 130..143
        #pragma unroll
        for (int e = 0; e < 8; ++e) v[e] = 0.0f;
    }

    uint4 u;
    u.x = pk_bf16(v[0], v[1]);
    u.y = pk_bf16(v[2], v[3]);
    u.z = pk_bf16(v[4], v[5]);
    u.w = pk_bf16(v[6], v[7]);
    afrag[g] = u;
}

// Main: 2048 blocks x 256 threads = 8192 waves; wave wv owns rows [wv*16, wv*16+16).
// No LDS, no barriers. C[d'][i]: A = musT' frags (precomputed), B = r row frags.
__global__ __launch_bounds__(256, 4)
void isoloss_kernel(const float* __restrict__ X,
                    const float* __restrict__ r,
                    const uint4* __restrict__ afrag,
                    float* __restrict__ ws)
{
    const int tid  = threadIdx.x;
    const int wv   = blockIdx.x * 4 + (tid >> 6);   // global wave 0..8191
    const int lane = tid & 63;
    const int li   = lane & 15;                     // row-in-chunk i (C col)
    const int kg   = lane >> 4;                     // k-group 0..3 (C row-group)

    const size_t i = (size_t)wv * 16 + li;
    const float* rrow_p = r + i * 128 + kg * 8;     // this lane's k-slices of r row i
    const float* xrow_p = X + i * 128 + kg * 4;     // this lane's d-slices of X row i

    // ---- prologue: issue r (8), X (8), af tile-0 (4) loads: 20 VMEM in flight ----
    float4 ra[8];
    #pragma unroll
    for (int ks = 0; ks < 4; ++ks) {
        ra[2*ks]   = *(const float4*)(rrow_p + ks * 32);
        ra[2*ks+1] = *(const float4*)(rrow_p + ks * 32 + 4);
    }
    float4 xv[8];
    #pragma unroll
    for (int dt = 0; dt < 8; ++dt)
        xv[dt] = *(const float4*)(xrow_p + dt * 16);

    short8 afc[4], afn[4];
    #pragma unroll
    for (int ks = 0; ks < 4; ++ks)
        afc[ks] = ((const short8*)afrag)[ks * 64 + lane];

    // ---- pack bfrag (waits only on r; X + af still in flight) ----
    short8 bfrag[4];
    #pragma unroll
    for (int ks = 0; ks < 4; ++ks) {
        union { short8 s8; uint4 u4; } u;
        u.u4.x = pk_bf16(ra[2*ks].x,   ra[2*ks].y);
        u.u4.y = pk_bf16(ra[2*ks].z,   ra[2*ks].w);
        u.u4.z = pk_bf16(ra[2*ks+1].x, ra[2*ks+1].y);
        u.u4.w = pk_bf16(ra[2*ks+1].z, ra[2*ks+1].w);
        bfrag[ks] = u.s8;
    }

    float dotp = 0.0f, x2p = 0.0f, rmu2v = 0.0f, rrowv = 0.0f;

    // ---- 9 d'-tiles, af double-buffered: prefetch dt+1 while dt's MFMAs run ----
    #pragma unroll
    for (int dt = 0; dt < 9; ++dt) {
        if (dt < 8) {
            #pragma unroll
            for (int ks = 0; ks < 4; ++ks)
                afn[ks] = ((const short8*)afrag)[((dt + 1) * 4 + ks) * 64 + lane];
        }

        float4v acc = {};
        #pragma unroll
        for (int ks = 0; ks < 4; ++ks)
            acc = __builtin_amdgcn_mfma_f32_16x16x32_bf16(afc[ks], bfrag[ks], acc, 0, 0, 0);

        if (dt < 8) {
            // acc[j] = y[dt*16 + kg*4 + j] for row i; X slice already in xv[dt].
            const float4 xq = xv[dt];
            dotp += xq.x*acc[0] + xq.y*acc[1] + xq.z*acc[2] + xq.w*acc[3];
            x2p  += xq.x*xq.x + xq.y*xq.y + xq.z*xq.z + xq.w*xq.w;
        } else {
            // aug tile: d'=128 (mu2 row) -> acc[0], d'=129 (ones) -> acc[1], kg==0;
            // kg>=1 lanes hit zero-pad rows -> zero contribution.
            rmu2v = (kg == 0) ? acc[0] : 0.0f;
            rrowv = (kg == 0) ? acc[1] : 0.0f;
        }

        #pragma unroll
        for (int ks = 0; ks < 4; ++ks) afc[ks] = afn[ks];   // static rotate
    }

    // full x2_i: butterfly over the 4 lanes (kg=0..3) holding row i's d-slices
    float x2i = x2p;
    x2i += __shfl_xor(x2i, 16);
    x2i += __shfl_xor(x2i, 32);

    // per-lane partial of loss*N
    float s = fmaf(-2.0f, dotp, fmaf(x2i, rrowv, rmu2v));

    // ---- wave reduce -> bucketed atomic ----
    #pragma unroll
    for (int off = 32; off > 0; off >>= 1) s += __shfl_down(s, off);
    if (lane == 0) atomicAdd(&ws[blockIdx.x & 63], s);
}

extern "C" void kernel_launch(void* const* d_in, const int* in_sizes, int n_in,
                              void* d_out, int out_size, void* d_ws, size_t ws_size,
                              hipStream_t stream) {
    const float* X   = (const float*)d_in[0];   // [131072, 128]
    const float* r   = (const float*)d_in[1];   // [131072, 128]
    const float* mus = (const float*)d_in[2];   // [128, 128]
    float* out = (float*)d_out;                 // scalar
    float* ws  = (float*)d_ws;                  // [0..64): buckets; +256B: afrag (36 KB)
    uint4* afrag = (uint4*)((char*)d_ws + 256);

    build_afrag_kernel<<<9, 256, 0, stream>>>(mus, afrag, ws);
    isoloss_kernel<<<2048, 256, 0, stream>>>(X, r, afrag, ws);
    final_reduce_kernel<<<1, 64, 0, stream>>>(ws, out);
}

// Round 8
// 184.200 us; speedup vs baseline: 1.1587x; 1.0212x over previous
//
#include <hip/hip_runtime.h>
#include <hip/hip_bf16.h>

// IsometricLoss: loss = (1/N) * sum_{i,m} r[i,m] * max(||X_i||^2 + ||mu_m||^2 - 2 X_i.mu_m, 0)
// N=131072, M=128, D=128, fp32 in, fp32 scalar out.
//
// R11: R10 + sched_barrier fences. R10 was clean (no spill, minimal fetch) but
// VGPR_Count=36 proved the LLVM scheduler SANK the prologue's 20 loads to their
// uses (can't hold 80 regs of payload in 36), re-serializing the latency chain
// -> 1.9 TB/s delivered. launch_bounds only CAPS regs; sched_barrier(0) pins
// the schedule: (1) all prologue loads (af, r, X - af first for counted vmcnt
// waits) issue before any pack; (2) in-loop afn prefetch issues before the
// tile's MFMAs. Forced live set ~95 regs < 128 cap (256,4) -> no spill.
// Math/layout identical to R8/R10 (verified).

typedef __attribute__((ext_vector_type(8))) short  short8;   // 8 bf16 (MFMA A/B frag)
typedef __attribute__((ext_vector_type(4))) float  float4v;  // MFMA 16x16 accumulator

#if defined(__has_builtin)
#if __has_builtin(__builtin_amdgcn_cvt_pk_bf16_f32)
#define HAVE_PK_BF16 1
#endif
#if __has_builtin(__builtin_amdgcn_sched_barrier)
#define SCHED_FENCE() __builtin_amdgcn_sched_barrier(0)
#endif
#endif
#ifndef SCHED_FENCE
#define SCHED_FENCE()
#endif

__device__ __forceinline__ unsigned int pk_bf16(float x, float y) {
#ifdef HAVE_PK_BF16
    typedef __attribute__((ext_vector_type(2))) __bf16 bf16x2;
    bf16x2 p = __builtin_amdgcn_cvt_pk_bf16_f32(x, y);
    return __builtin_bit_cast(unsigned int, p);
#else
    unsigned int ux = __float_as_uint(x);
    unsigned int uy = __float_as_uint(y);
    ux += 0x7fffu + ((ux >> 16) & 1u);
    uy += 0x7fffu + ((uy >> 16) & 1u);
    return (ux >> 16) | (uy & 0xffff0000u);
#endif
}

__global__ void final_reduce_kernel(const float* ws, float* out) {
    const int lane = threadIdx.x;  // 64 threads
    float t = ws[lane];
    #pragma unroll
    for (int off = 32; off > 0; off >>= 1) t += __shfl_down(t, off);
    if (lane == 0) out[0] = t * (1.0f / 131072.0f);
}

// Prelude: lane-packed A-fragment table for musT' [144 x 128] bf16.
// Entry g = (dt*4 + ks)*64 + lane holds 8 bf16:
//   musT'[dt*16 + (lane&15)][ks*32 + (lane>>4)*8 + e],  dt=0..8, ks=0..3.
// Rows: 0..127 = mus^T, 128 = mu2 (exact fp32), 129 = ones, 130..143 = 0.
// Block 0 also zeroes the 64 reduction buckets.
__global__ __launch_bounds__(256)
void build_afrag_kernel(const float* __restrict__ mus, uint4* __restrict__ afrag,
                        float* __restrict__ ws)
{
    const int g = blockIdx.x * 256 + threadIdx.x;   // 0..2303 (9 blocks)
    if (blockIdx.x == 0 && threadIdx.x < 64) ws[threadIdx.x] = 0.0f;

    const int dt   = g >> 8;         // 0..8
    const int ks   = (g >> 6) & 3;
    const int lane = g & 63;
    const int dp   = dt * 16 + (lane & 15);          // d' in [0,144)
    const int m0   = ks * 32 + (lane >> 4) * 8;      // m base

    float v[8];
    if (dp < 128) {
        #pragma unroll
        for (int e = 0; e < 8; ++e)
            v[e] = mus[(size_t)(m0 + e) * 128 + dp];       // musT[d'][m] = mus[m][d']
    } else if (dp == 128) {                                // mu2 row (exact fp32 sums)
        #pragma unroll
        for (int e = 0; e < 8; ++e) {
            const float4* row = (const float4*)(mus + (size_t)(m0 + e) * 128);
            float a = 0.0f;
            #pragma unroll 8
            for (int d4 = 0; d4 < 32; ++d4) {
                const float4 t = row[d4];
                a += t.x*t.x + t.y*t.y + t.z*t.z + t.w*t.w;
            }
            v[e] = a;
        }
    } else if (dp == 129) {                                // ones row -> rrow
        #pragma unroll
        for (int e = 0; e < 8; ++e) v[e] = 1.0f;
    } else {                                               // zero pad rows 130..143
        #pragma unroll
        for (int e = 0; e < 8; ++e) v[e] = 0.0f;
    }

    uint4 u;
    u.x = pk_bf16(v[0], v[1]);
    u.y = pk_bf16(v[2], v[3]);
    u.z = pk_bf16(v[4], v[5]);
    u.w = pk_bf16(v[6], v[7]);
    afrag[g] = u;
}

// Main: 2048 blocks x 256 threads = 8192 waves; wave wv owns rows [wv*16, wv*16+16).
// No LDS, no barriers. C[d'][i]: A = musT' frags (precomputed), B = r row frags.
__global__ __launch_bounds__(256, 4)
void isoloss_kernel(const float* __restrict__ X,
                    const float* __restrict__ r,
                    const uint4* __restrict__ afrag,
                    float* __restrict__ ws)
{
    const int tid  = threadIdx.x;
    const int wv   = blockIdx.x * 4 + (tid >> 6);   // global wave 0..8191
    const int lane = tid & 63;
    const int li   = lane & 15;                     // row-in-chunk i (C col)
    const int kg   = lane >> 4;                     // k-group 0..3 (C row-group)

    const size_t i = (size_t)wv * 16 + li;
    const float* rrow_p = r + i * 128 + kg * 8;     // this lane's k-slices of r row i
    const float* xrow_p = X + i * 128 + kg * 4;     // this lane's d-slices of X row i

    // ---- prologue: issue af tile-0 (4), r (8), X (8): 20 VMEM in flight ----
    // Order af->r->X so consuming bfrag/MFMA uses COUNTED vmcnt waits (X still
    // in flight during tile-0 MFMA), not a full drain.
    short8 afc[4], afn[4];
    #pragma unroll
    for (int ks = 0; ks < 4; ++ks)
        afc[ks] = ((const short8*)afrag)[ks * 64 + lane];

    float4 ra[8];
    #pragma unroll
    for (int ks = 0; ks < 4; ++ks) {
        ra[2*ks]   = *(const float4*)(rrow_p + ks * 32);
        ra[2*ks+1] = *(const float4*)(rrow_p + ks * 32 + 4);
    }
    float4 xv[8];
    #pragma unroll
    for (int dt = 0; dt < 8; ++dt)
        xv[dt] = *(const float4*)(xrow_p + dt * 16);

    SCHED_FENCE();  // pin: all 20 loads issued before ANY consumption (R10's VGPR=36 proved the scheduler sank them)

    // ---- pack bfrag (counted wait on r; X still in flight) ----
    short8 bfrag[4];
    #pragma unroll
    for (int ks = 0; ks < 4; ++ks) {
        union { short8 s8; uint4 u4; } u;
        u.u4.x = pk_bf16(ra[2*ks].x,   ra[2*ks].y);
        u.u4.y = pk_bf16(ra[2*ks].z,   ra[2*ks].w);
        u.u4.z = pk_bf16(ra[2*ks+1].x, ra[2*ks+1].y);
        u.u4.w = pk_bf16(ra[2*ks+1].z, ra[2*ks+1].w);
        bfrag[ks] = u.s8;
    }

    float dotp = 0.0f, x2p = 0.0f, rmu2v = 0.0f, rrowv = 0.0f;

    // ---- 9 d'-tiles, af double-buffered: prefetch dt+1 pinned BEFORE dt's MFMAs ----
    #pragma unroll
    for (int dt = 0; dt < 9; ++dt) {
        if (dt < 8) {
            #pragma unroll
            for (int ks = 0; ks < 4; ++ks)
                afn[ks] = ((const short8*)afrag)[((dt + 1) * 4 + ks) * 64 + lane];
            SCHED_FENCE();  // afn issue may not sink below the MFMAs
        }

        float4v acc = {};
        #pragma unroll
        for (int ks = 0; ks < 4; ++ks)
            acc = __builtin_amdgcn_mfma_f32_16x16x32_bf16(afc[ks], bfrag[ks], acc, 0, 0, 0);

        if (dt < 8) {
            // acc[j] = y[dt*16 + kg*4 + j] for row i; X slice already in xv[dt].
            const float4 xq = xv[dt];
            dotp += xq.x*acc[0] + xq.y*acc[1] + xq.z*acc[2] + xq.w*acc[3];
            x2p  += xq.x*xq.x + xq.y*xq.y + xq.z*xq.z + xq.w*xq.w;
        } else {
            // aug tile: d'=128 (mu2 row) -> acc[0], d'=129 (ones) -> acc[1], kg==0;
            // kg>=1 lanes hit zero-pad rows -> zero contribution.
            rmu2v = (kg == 0) ? acc[0] : 0.0f;
            rrowv = (kg == 0) ? acc[1] : 0.0f;
        }

        #pragma unroll
        for (int ks = 0; ks < 4; ++ks) afc[ks] = afn[ks];   // static rotate
    }

    // full x2_i: butterfly over the 4 lanes (kg=0..3) holding row i's d-slices
    float x2i = x2p;
    x2i += __shfl_xor(x2i, 16);
    x2i += __shfl_xor(x2i, 32);

    // per-lane partial of loss*N
    float s = fmaf(-2.0f, dotp, fmaf(x2i, rrowv, rmu2v));

    // ---- wave reduce -> bucketed atomic ----
    #pragma unroll
    for (int off = 32; off > 0; off >>= 1) s += __shfl_down(s, off);
    if (lane == 0) atomicAdd(&ws[blockIdx.x & 63], s);
}

extern "C" void kernel_launch(void* const* d_in, const int* in_sizes, int n_in,
                              void* d_out, int out_size, void* d_ws, size_t ws_size,
                              hipStream_t stream) {
    const float* X   = (const float*)d_in[0];   // [131072, 128]
    const float* r   = (const float*)d_in[1];   // [131072, 128]
    const float* mus = (const float*)d_in[2];   // [128, 128]
    float* out = (float*)d_out;                 // scalar
    float* ws  = (float*)d_ws;                  // [0..64): buckets; +256B: afrag (36 KB)
    uint4* afrag = (uint4*)((char*)d_ws + 256);

    build_afrag_kernel<<<9, 256, 0, stream>>>(mus, afrag, ws);
    isoloss_kernel<<<2048, 256, 0, stream>>>(X, r, afrag, ws);
    final_reduce_kernel<<<1, 64, 0, stream>>>(ws, out);
}